// Round 1
// baseline (1005.500 us; speedup 1.0000x reference)
//
#include <hip/hip_runtime.h>

#define DIM 192
#define DD  (192 * 192)
#define DDD (192 * 192 * 192)
#define INV27 (1.0f / 27.0f)
#define EPS 1e-5f

// ---------------------------------------------------------------------------
// Pass 1: dF = F - boxmean(F), dM = M - boxmean(M)   (3x3x3, replicate pad)
// ---------------------------------------------------------------------------
__global__ __launch_bounds__(256) void diff_kernel(
    const float* __restrict__ F, const float* __restrict__ M,
    float* __restrict__ dF, float* __restrict__ dM)
{
    int v = blockIdx.x * 256 + threadIdx.x;            // v in [0, 2*DDD)
    int b = v / DDD;
    int r = v - b * DDD;
    int x = r % DIM;
    int y = (r / DIM) % DIM;
    int z = r / DD;

    const float* f = F + (size_t)b * DDD;
    const float* m = M + (size_t)b * DDD;

    int x0 = x > 0 ? x - 1 : 0, x2 = x < DIM - 1 ? x + 1 : DIM - 1;
    int y0 = y > 0 ? y - 1 : 0, y2 = y < DIM - 1 ? y + 1 : DIM - 1;
    int z0 = z > 0 ? z - 1 : 0, z2 = z < DIM - 1 ? z + 1 : DIM - 1;
    int zs[3] = {z0, z, z2};
    int ys[3] = {y0, y, y2};

    float sF = 0.f, sM = 0.f;
#pragma unroll
    for (int i = 0; i < 3; ++i) {
#pragma unroll
        for (int j = 0; j < 3; ++j) {
            int base = (zs[i] * DIM + ys[j]) * DIM;
            sF += f[base + x0] + f[base + x] + f[base + x2];
            sM += m[base + x0] + m[base + x] + m[base + x2];
        }
    }
    dF[v] = f[r] - sF * INV27;
    dM[v] = m[r] - sM * INV27;
}

// ---------------------------------------------------------------------------
// Pass 2: cross/varF/varM box sums -> z -> per-batch reduction
// ---------------------------------------------------------------------------
__global__ __launch_bounds__(256) void lcc_kernel(
    const float* __restrict__ dF, const float* __restrict__ dM,
    double* __restrict__ acc)
{
    int b = blockIdx.y;
    int r = blockIdx.x * 256 + threadIdx.x;            // r in [0, DDD)
    int x = r % DIM;
    int y = (r / DIM) % DIM;
    int z = r / DD;

    const float* pF = dF + (size_t)b * DDD;
    const float* pM = dM + (size_t)b * DDD;

    int x0 = x > 0 ? x - 1 : 0, x2 = x < DIM - 1 ? x + 1 : DIM - 1;
    int y0 = y > 0 ? y - 1 : 0, y2 = y < DIM - 1 ? y + 1 : DIM - 1;
    int z0 = z > 0 ? z - 1 : 0, z2 = z < DIM - 1 ? z + 1 : DIM - 1;
    int zs[3] = {z0, z, z2};
    int ys[3] = {y0, y, y2};
    int xs[3] = {x0, x, x2};

    float cc = 0.f, ff = 0.f, mm = 0.f;
#pragma unroll
    for (int i = 0; i < 3; ++i) {
#pragma unroll
        for (int j = 0; j < 3; ++j) {
            int base = (zs[i] * DIM + ys[j]) * DIM;
#pragma unroll
            for (int k = 0; k < 3; ++k) {
                float a = pF[base + xs[k]];
                float c = pM[base + xs[k]];
                cc += a * c;
                ff += a * a;
                mm += c * c;
            }
        }
    }
    float zv = cc * cc / (ff * mm + EPS);

    // block reduce (256 threads = 4 waves)
    float s = zv;
#pragma unroll
    for (int off = 32; off > 0; off >>= 1) s += __shfl_down(s, off, 64);
    __shared__ float wsum[4];
    int lane = threadIdx.x & 63;
    int wid  = threadIdx.x >> 6;
    if (lane == 0) wsum[wid] = s;
    __syncthreads();
    if (threadIdx.x == 0) {
        float t = wsum[0] + wsum[1] + wsum[2] + wsum[3];
        atomicAdd(&acc[b], (double)t);
    }
}

// ---------------------------------------------------------------------------
// Fallback (only if ws too small): recompute dF/dM on the fly (slow, correct)
// ---------------------------------------------------------------------------
__device__ __forceinline__ float2 dvals(const float* __restrict__ f,
                                        const float* __restrict__ m,
                                        int x, int y, int z)
{
    int x0 = x > 0 ? x - 1 : 0, x2 = x < DIM - 1 ? x + 1 : DIM - 1;
    int y0 = y > 0 ? y - 1 : 0, y2 = y < DIM - 1 ? y + 1 : DIM - 1;
    int z0 = z > 0 ? z - 1 : 0, z2 = z < DIM - 1 ? z + 1 : DIM - 1;
    int zs[3] = {z0, z, z2};
    int ys[3] = {y0, y, y2};
    float sF = 0.f, sM = 0.f;
#pragma unroll
    for (int i = 0; i < 3; ++i) {
#pragma unroll
        for (int j = 0; j < 3; ++j) {
            int base = (zs[i] * DIM + ys[j]) * DIM;
            sF += f[base + x0] + f[base + x] + f[base + x2];
            sM += m[base + x0] + m[base + x] + m[base + x2];
        }
    }
    int c = (z * DIM + y) * DIM + x;
    return make_float2(f[c] - sF * INV27, m[c] - sM * INV27);
}

__global__ __launch_bounds__(256) void lcc_direct_kernel(
    const float* __restrict__ F, const float* __restrict__ M,
    double* __restrict__ acc)
{
    int b = blockIdx.y;
    int r = blockIdx.x * 256 + threadIdx.x;
    int x = r % DIM;
    int y = (r / DIM) % DIM;
    int z = r / DD;

    const float* f = F + (size_t)b * DDD;
    const float* m = M + (size_t)b * DDD;

    int x0 = x > 0 ? x - 1 : 0, x2 = x < DIM - 1 ? x + 1 : DIM - 1;
    int y0 = y > 0 ? y - 1 : 0, y2 = y < DIM - 1 ? y + 1 : DIM - 1;
    int z0 = z > 0 ? z - 1 : 0, z2 = z < DIM - 1 ? z + 1 : DIM - 1;
    int zs[3] = {z0, z, z2};
    int ys[3] = {y0, y, y2};
    int xs[3] = {x0, x, x2};

    float cc = 0.f, ff = 0.f, mm = 0.f;
#pragma unroll
    for (int i = 0; i < 3; ++i)
#pragma unroll
        for (int j = 0; j < 3; ++j)
#pragma unroll
            for (int k = 0; k < 3; ++k) {
                float2 d = dvals(f, m, xs[k], ys[j], zs[i]);
                cc += d.x * d.y;
                ff += d.x * d.x;
                mm += d.y * d.y;
            }
    float zv = cc * cc / (ff * mm + EPS);

    float s = zv;
#pragma unroll
    for (int off = 32; off > 0; off >>= 1) s += __shfl_down(s, off, 64);
    __shared__ float wsum[4];
    int lane = threadIdx.x & 63;
    int wid  = threadIdx.x >> 6;
    if (lane == 0) wsum[wid] = s;
    __syncthreads();
    if (threadIdx.x == 0) {
        float t = wsum[0] + wsum[1] + wsum[2] + wsum[3];
        atomicAdd(&acc[b], (double)t);
    }
}

// ---------------------------------------------------------------------------
// Finalize: out[b] = -acc[b] / N
// ---------------------------------------------------------------------------
__global__ void finalize_kernel(const double* __restrict__ acc,
                                float* __restrict__ out)
{
    int i = threadIdx.x;
    if (i < 2) out[i] = (float)(-acc[i] / (double)DDD);
}

extern "C" void kernel_launch(void* const* d_in, const int* in_sizes, int n_in,
                              void* d_out, int out_size, void* d_ws, size_t ws_size,
                              hipStream_t stream)
{
    const float* F = (const float*)d_in[0];   // im_fixed  [2,1,192,192,192] f32
    const float* M = (const float*)d_in[1];   // im_moving
    float* out = (float*)d_out;               // [2] f32

    double* acc = (double*)d_ws;              // 2 doubles at ws start
    hipMemsetAsync(d_ws, 0, 2 * sizeof(double), stream);

    size_t need = 256 + (size_t)2 * 2 * DDD * sizeof(float);
    if (ws_size >= need) {
        float* dF = (float*)((char*)d_ws + 256);
        float* dM = dF + (size_t)2 * DDD;
        // 2*DDD / 256 = 110592 blocks
        diff_kernel<<<2 * DDD / 256, 256, 0, stream>>>(F, M, dF, dM);
        dim3 g(DDD / 256, 2);
        lcc_kernel<<<g, 256, 0, stream>>>(dF, dM, acc);
    } else {
        dim3 g(DDD / 256, 2);
        lcc_direct_kernel<<<g, 256, 0, stream>>>(F, M, acc);
    }
    finalize_kernel<<<1, 64, 0, stream>>>(acc, out);
}

// Round 2
// 233.273 us; speedup vs baseline: 4.3104x; 4.3104x over previous
//
#include <hip/hip_runtime.h>

#define DIM 192
#define DD  (DIM * DIM)
#define DDD (DIM * DIM * DIM)
#define INV27 (1.0f / 27.0f)
#define EPS 1e-5f

#define TX 32
#define TY 8
#define X1 (TX + 2)   // 34 halo-1 width
#define Y1 (TY + 2)   // 10 halo-1 height
#define X2 (TX + 4)   // 36 halo-2 width
#define Y2 (TY + 4)   // 12 halo-2 height
#define ZC 48         // z-chunk per block

#define NLOAD (X2 * Y2)   // 432
#define NRS   (X1 * Y2)   // 408
#define NS2   (X1 * Y1)   // 340
#define NPX   (TX * Y1)   // 320

__device__ __forceinline__ int iclamp(int v, int hi) {
    return v < 0 ? 0 : (v > hi ? hi : v);
}

// ---------------------------------------------------------------------------
// Fully fused LCC: per block an (TX x TY) xy-tile over a z-chunk.
// Pipeline per z-plane zc:
//   s1: load F,M plane (halo2) -> LDS           s2: x row-sums (halo1 x, halo2 y)
//   s3: y col-sums -> SF2D ring + center vals    s4: dF,dM + products (plane zc-1)
//   s5: x row-sums of products                   s6: y col-sums -> per-thread PS ring,
//                                                    z-window output, accumulate z
// ---------------------------------------------------------------------------
__global__ __launch_bounds__(256) void lcc_fused(
    const float* __restrict__ F, const float* __restrict__ M,
    double* __restrict__ acc)
{
    __shared__ float ftmp[NLOAD], mtmp[NLOAD];
    __shared__ float rsF[NRS], rsM[NRS];
    __shared__ float SF[3][NS2], SM[3][NS2];     // 2D 9-sums, z-ring
    __shared__ float FV[3][NS2], MV[3][NS2];     // center values, z-ring
    __shared__ float prodc[NS2], prodf[NS2], prodm[NS2];
    __shared__ float prxc[NPX], prxf[NPX], prxm[NPX];
    __shared__ float wred[4];

    const int tid = threadIdx.x;
    const int xt = blockIdx.y % (DIM / TX);
    const int yt = blockIdx.y / (DIM / TX);
    const int x0 = xt * TX, y0 = yt * TY;
    const int z0 = blockIdx.x * ZC;
    const int z1 = z0 + ZC;
    const int b  = blockIdx.z;

    const float* f = F + (size_t)b * DDD;
    const float* m = M + (size_t)b * DDD;

    // ---- per-thread precomputed indices (z-invariant) ----
    // s1: load (points tid, tid+256 of 432)
    int lg0, lg1; bool la1;
    {
        int l = tid, lx = l % X2, ly = l / X2;
        lg0 = iclamp(y0 - 2 + ly, DIM - 1) * DIM + iclamp(x0 - 2 + lx, DIM - 1);
        l = tid + 256; la1 = (l < NLOAD);
        lg1 = 0;
        if (la1) {
            lx = l % X2; ly = l / X2;
            lg1 = iclamp(y0 - 2 + ly, DIM - 1) * DIM + iclamp(x0 - 2 + lx, DIM - 1);
        }
    }
    // s2: rowsum (points of 408): read ftmp[ly*X2 + x1 .. +2], write rs[l]
    int rrd0, rrd1; bool ra1;
    {
        int l = tid; rrd0 = (l / X1) * X2 + (l % X1);
        l = tid + 256; ra1 = (l < NRS);
        rrd1 = ra1 ? (l / X1) * X2 + (l % X1) : 0;
    }
    // s3: SF2D (points of 340): read rs[l, l+X1, l+2*X1], write SF[s][l];
    //     center value read ftmp[(y1+1)*X2 + x1+1]
    int fvr0, fvr1; bool sa1;
    {
        int l = tid; fvr0 = (l / X1 + 1) * X2 + (l % X1 + 1);
        l = tid + 256; sa1 = (l < NS2);
        fvr1 = sa1 ? (l / X1 + 1) * X2 + (l % X1 + 1) : 0;
    }
    // s4: products (points of 340): read SF/FV at clamped-center slot, write prod[l]
    int prd0, prd1; bool pa1;
    {
        int l = tid, x1 = l % X1, y1 = l / X1;
        int x1c = iclamp(x0 - 1 + x1, DIM - 1) - (x0 - 1);
        int y1c = iclamp(y0 - 1 + y1, DIM - 1) - (y0 - 1);
        prd0 = y1c * X1 + x1c;
        l = tid + 256; pa1 = (l < NS2);
        prd1 = 0;
        if (pa1) {
            x1 = l % X1; y1 = l / X1;
            x1c = iclamp(x0 - 1 + x1, DIM - 1) - (x0 - 1);
            y1c = iclamp(y0 - 1 + y1, DIM - 1) - (y0 - 1);
            prd1 = y1c * X1 + x1c;
        }
    }
    // s5: prod x-rowsum (points of 320): read prod[py*X1 + px .. +2], write prx[l]
    int xrd0, xrd1; bool xa1;
    {
        int l = tid; xrd0 = (l / TX) * X1 + (l % TX);
        l = tid + 256; xa1 = (l < NPX);
        xrd1 = xa1 ? (l / TX) * X1 + (l % TX) : 0;
    }
    // s6: colsum at own tile point: prx rows ty..ty+2 at col tx -> crd = tid
    const int crd = tid;

    const int zpLo = (z0 - 1 > 0) ? z0 - 1 : 0;
    const int zpHi = (z1 < DIM - 1) ? z1 : DIM - 1;
    const int zcStart = (z0 - 2 > -1) ? z0 - 2 : -1;

    float pm0 = 0, pm1 = 0, pm2 = 0;   // PS(z-1)
    float pc0 = 0, pc1 = 0, pc2 = 0;   // PS(z)
    float pn0 = 0, pn1 = 0, pn2 = 0;   // PS(z+1)
    float accz = 0.f;

    for (int zc = zcStart; zc <= z1 + 1; ++zc) {
        const int zcl = iclamp(zc, DIM - 1);
        const size_t zoff = (size_t)zcl * DD;

        // ---- s1: load plane into LDS ----
        ftmp[tid] = f[zoff + lg0];
        mtmp[tid] = m[zoff + lg0];
        if (la1) { ftmp[tid + 256] = f[zoff + lg1]; mtmp[tid + 256] = m[zoff + lg1]; }
        __syncthreads();

        // ---- s2: x row-sums ----
        rsF[tid] = ftmp[rrd0] + ftmp[rrd0 + 1] + ftmp[rrd0 + 2];
        rsM[tid] = mtmp[rrd0] + mtmp[rrd0 + 1] + mtmp[rrd0 + 2];
        if (ra1) {
            rsF[tid + 256] = ftmp[rrd1] + ftmp[rrd1 + 1] + ftmp[rrd1 + 2];
            rsM[tid + 256] = mtmp[rrd1] + mtmp[rrd1 + 1] + mtmp[rrd1 + 2];
        }
        __syncthreads();

        // ---- s3: y col-sums (2D 9-sum) + center values into ring slot ----
        const int s = (zc + 3) % 3;
        SF[s][tid] = rsF[tid] + rsF[tid + X1] + rsF[tid + 2 * X1];
        SM[s][tid] = rsM[tid] + rsM[tid + X1] + rsM[tid + 2 * X1];
        FV[s][tid] = ftmp[fvr0];
        MV[s][tid] = mtmp[fvr0];
        if (sa1) {
            const int l = tid + 256;
            SF[s][l] = rsF[l] + rsF[l + X1] + rsF[l + 2 * X1];
            SM[s][l] = rsM[l] + rsM[l + X1] + rsM[l + 2 * X1];
            FV[s][l] = ftmp[fvr1];
            MV[s][l] = mtmp[fvr1];
        }
        __syncthreads();

        // ---- s4: dF, dM, products for plane zp = zc-1 ----
        const int zp = zc - 1;
        const bool stage = (zp >= zpLo);           // block-uniform
        const bool live  = stage && (zp <= zpHi);  // block-uniform
        if (live) {
            const int sm_ = (zp + 2) % 3, s0_ = zp % 3, sp_ = (zp + 1) % 3;
            {
                float bf = (SF[sm_][prd0] + SF[s0_][prd0] + SF[sp_][prd0]) * INV27;
                float bm = (SM[sm_][prd0] + SM[s0_][prd0] + SM[sp_][prd0]) * INV27;
                float dFv = FV[s0_][prd0] - bf;
                float dMv = MV[s0_][prd0] - bm;
                prodc[tid] = dFv * dMv; prodf[tid] = dFv * dFv; prodm[tid] = dMv * dMv;
            }
            if (pa1) {
                float bf = (SF[sm_][prd1] + SF[s0_][prd1] + SF[sp_][prd1]) * INV27;
                float bm = (SM[sm_][prd1] + SM[s0_][prd1] + SM[sp_][prd1]) * INV27;
                float dFv = FV[s0_][prd1] - bf;
                float dMv = MV[s0_][prd1] - bm;
                prodc[tid + 256] = dFv * dMv;
                prodf[tid + 256] = dFv * dFv;
                prodm[tid + 256] = dMv * dMv;
            }
        }
        __syncthreads();

        // ---- s5: x row-sums of products ----
        if (live) {
            prxc[tid] = prodc[xrd0] + prodc[xrd0 + 1] + prodc[xrd0 + 2];
            prxf[tid] = prodf[xrd0] + prodf[xrd0 + 1] + prodf[xrd0 + 2];
            prxm[tid] = prodm[xrd0] + prodm[xrd0 + 1] + prodm[xrd0 + 2];
            if (xa1) {
                prxc[tid + 256] = prodc[xrd1] + prodc[xrd1 + 1] + prodc[xrd1 + 2];
                prxf[tid + 256] = prodf[xrd1] + prodf[xrd1 + 1] + prodf[xrd1 + 2];
                prxm[tid + 256] = prodm[xrd1] + prodm[xrd1 + 1] + prodm[xrd1 + 2];
            }
        }
        __syncthreads();

        // ---- s6: y col-sums -> PS ring; z-window -> output ----
        if (stage) {
            // shift z-ring
            pm0 = pc0; pm1 = pc1; pm2 = pc2;
            pc0 = pn0; pc1 = pn1; pc2 = pn2;
            if (live) {
                pn0 = prxc[crd] + prxc[crd + TX] + prxc[crd + 2 * TX];
                pn1 = prxf[crd] + prxf[crd + TX] + prxf[crd + 2 * TX];
                pn2 = prxm[crd] + prxm[crd + TX] + prxm[crd + 2 * TX];
            }
            const int z = zc - 2;
            if (z >= z0 && z < z1) {
                // replicate padding of the SECOND box stage in z:
                // PS(-1) := PS(0), PS(192) := PS(191)
                float a0 = (z == 0)       ? pc0 : pm0;
                float a1 = (z == 0)       ? pc1 : pm1;
                float a2 = (z == 0)       ? pc2 : pm2;
                float c0 = (z == DIM - 1) ? pc0 : pn0;
                float c1 = (z == DIM - 1) ? pc1 : pn1;
                float c2 = (z == DIM - 1) ? pc2 : pn2;
                float cross = a0 + pc0 + c0;
                float varF  = a1 + pc1 + c1;
                float varM  = a2 + pc2 + c2;
                accz += cross * cross / (varF * varM + EPS);
            }
        }
    }

    // ---- block reduction -> global accumulator ----
    float sred = accz;
#pragma unroll
    for (int off = 32; off > 0; off >>= 1) sred += __shfl_down(sred, off, 64);
    if ((tid & 63) == 0) wred[tid >> 6] = sred;
    __syncthreads();
    if (tid == 0)
        atomicAdd(&acc[b], (double)(wred[0] + wred[1] + wred[2] + wred[3]));
}

__global__ void finalize_kernel(const double* __restrict__ acc,
                                float* __restrict__ out)
{
    int i = threadIdx.x;
    if (i < 2) out[i] = (float)(-acc[i] / (double)DDD);
}

extern "C" void kernel_launch(void* const* d_in, const int* in_sizes, int n_in,
                              void* d_out, int out_size, void* d_ws, size_t ws_size,
                              hipStream_t stream)
{
    const float* F = (const float*)d_in[0];   // im_fixed  [2,1,192,192,192] f32
    const float* M = (const float*)d_in[1];   // im_moving
    float* out = (float*)d_out;               // [2] f32

    double* acc = (double*)d_ws;
    hipMemsetAsync(d_ws, 0, 2 * sizeof(double), stream);

    dim3 grid(DIM / ZC, (DIM / TX) * (DIM / TY), 2);   // 4 x 144 x 2 = 1152 blocks
    lcc_fused<<<grid, 256, 0, stream>>>(F, M, acc);
    finalize_kernel<<<1, 64, 0, stream>>>(acc, out);
}

// Round 3
// 211.597 us; speedup vs baseline: 4.7520x; 1.1024x over previous
//
#include <hip/hip_runtime.h>

#define DIM 192
#define DD  (DIM * DIM)
#define DDD (DIM * DIM * DIM)
#define INV27 (1.0f / 27.0f)
#define EPS 1e-5f

#define TY 8          // output rows per block (1 per wave)
#define ZC 12         // output planes per block -> 16 z-chunks, grid 768
#define NRS (TY + 4)  // 12 rowsum slots
#define NPR (TY + 2)  // 10 product slots

__device__ __forceinline__ int iclamp(int v, int hi) {
    return v < 0 ? 0 : (v > hi ? hi : v);
}

// ---------------------------------------------------------------------------
// Wave-per-row fused LCC.
// Lane t owns x = 3t..3t+2. Per z-plane:
//   stage1: load row (global, float3) -> x-rowsums (2 shuffles) -> LDS (b96)
//   barrier
//   S2D push: read 3 rowsum rows -> per-wave register z-ring
//   products (plane zc-1): box3d from ring + center reload (L1-hot) ->
//     dF,dM -> 3 products -> x-rowsums (shuffles) -> PRS in LDS (b96)
//   barrier
//   output (plane zc-2): read 3 PRS rows -> PS z-ring -> z-window -> accumulate
// ---------------------------------------------------------------------------
__global__ __launch_bounds__(512) void lcc_fused(
    const float* __restrict__ F, const float* __restrict__ M,
    double* __restrict__ acc)
{
    __shared__ float RSf[NRS][DIM];
    __shared__ float RSm[NRS][DIM];
    __shared__ float PRS[3][NPR][DIM];   // quantities: 0=cross 1=ff 2=mm
    __shared__ float wred[8];

    const int tid = threadIdx.x;
    const int w   = tid >> 6;     // wave 0..7
    const int t   = tid & 63;     // lane
    const int x   = 3 * t;

    const int y0 = blockIdx.y * TY;
    const int z0 = blockIdx.x * ZC;
    const int z1 = z0 + ZC;
    const int b  = blockIdx.z;

    const float* f = F + (size_t)b * DDD;
    const float* m = M + (size_t)b * DDD;

    // ---- stage-1 rowsum tasks: slot s holds row clamp(y0-2+s) ----
    const int  row1a = iclamp(y0 - 2 + w, DIM - 1);         // slot w
    const bool has1b = (w < NRS - 8);                       // waves 0..3
    const int  row1b = iclamp(y0 + 6 + w, DIM - 1);         // slot 8+w

    // ---- product tasks: slot tt holds product row clamp(y0-1+tt) ----
    const int  tA    = w + 1;
    const int  prowA = iclamp(y0 - 1 + tA, DIM - 1);
    const bool hasB  = (w == 0) || (w == 7);
    const int  tB    = (w == 0) ? 0 : NPR - 1;
    const int  prowB = iclamp(y0 - 1 + tB, DIM - 1);

    // S2D y-window RS slots (double-clamped): slot = clamp(row+dy) - y0 + 2
    const int sAm = iclamp(prowA - 1, DIM - 1) - y0 + 2;
    const int sAc = prowA - y0 + 2;
    const int sAp = iclamp(prowA + 1, DIM - 1) - y0 + 2;
    const int sBm = iclamp(prowB - 1, DIM - 1) - y0 + 2;
    const int sBc = prowB - y0 + 2;
    const int sBp = iclamp(prowB + 1, DIM - 1) - y0 + 2;

    // ---- output row & its PRS window slots ----
    const int yo  = y0 + w;
    const int tOm = iclamp(yo - 1, DIM - 1) - y0 + 1;
    const int tOc = w + 1;
    const int tOp = iclamp(yo + 1, DIM - 1) - y0 + 1;

    const int zpLo = (z0 - 1 > 0) ? z0 - 1 : 0;
    const int zpHi = (z1 < DIM - 1) ? z1 : DIM - 1;
    const int zcStart = (z0 - 2 > -1) ? z0 - 2 : -1;

    // per-wave register rings
    float rAf[3][3], rAm[3][3], rBf[3][3], rBm[3][3];   // S2D rings [z][xpt]
    float pmv[9], pcv[9], pnv[9];                       // PS rings [q*3+xpt]
#pragma unroll
    for (int i = 0; i < 3; ++i)
#pragma unroll
        for (int j = 0; j < 3; ++j) {
            rAf[i][j] = 0.f; rAm[i][j] = 0.f; rBf[i][j] = 0.f; rBm[i][j] = 0.f;
        }
#pragma unroll
    for (int i = 0; i < 9; ++i) { pmv[i] = 0.f; pcv[i] = 0.f; pnv[i] = 0.f; }

    float accz = 0.f;

    for (int zc = zcStart; zc <= z1 + 1; ++zc) {
        const int zcl = iclamp(zc, DIM - 1);
        const size_t zoff = (size_t)zcl * DD;

        // ---------------- stage 1: x-rowsums -> LDS ----------------
        {
            const float* fr = f + zoff + (size_t)row1a * DIM + x;
            const float* mr = m + zoff + (size_t)row1a * DIM + x;
            float a0 = fr[0], a1 = fr[1], a2 = fr[2];
            float c0 = mr[0], c1 = mr[1], c2 = mr[2];
            float aL = __shfl(a2, t - 1); aL = (t == 0)  ? a0 : aL;
            float aR = __shfl(a0, t + 1); aR = (t == 63) ? a2 : aR;
            float cL = __shfl(c2, t - 1); cL = (t == 0)  ? c0 : cL;
            float cR = __shfl(c0, t + 1); cR = (t == 63) ? c2 : cR;
            *(float3*)&RSf[w][x] = make_float3(aL + a0 + a1, a0 + a1 + a2, a1 + a2 + aR);
            *(float3*)&RSm[w][x] = make_float3(cL + c0 + c1, c0 + c1 + c2, c1 + c2 + cR);
        }
        if (has1b) {
            const float* fr = f + zoff + (size_t)row1b * DIM + x;
            const float* mr = m + zoff + (size_t)row1b * DIM + x;
            float a0 = fr[0], a1 = fr[1], a2 = fr[2];
            float c0 = mr[0], c1 = mr[1], c2 = mr[2];
            float aL = __shfl(a2, t - 1); aL = (t == 0)  ? a0 : aL;
            float aR = __shfl(a0, t + 1); aR = (t == 63) ? a2 : aR;
            float cL = __shfl(c2, t - 1); cL = (t == 0)  ? c0 : cL;
            float cR = __shfl(c0, t + 1); cR = (t == 63) ? c2 : cR;
            *(float3*)&RSf[8 + w][x] = make_float3(aL + a0 + a1, a0 + a1 + a2, a1 + a2 + aR);
            *(float3*)&RSm[8 + w][x] = make_float3(cL + c0 + c1, c0 + c1 + c2, c1 + c2 + cR);
        }
        __syncthreads();

        // ---------------- S2D ring pushes ----------------
        {
            float3 q0 = *(const float3*)&RSf[sAm][x];
            float3 q1 = *(const float3*)&RSf[sAc][x];
            float3 q2 = *(const float3*)&RSf[sAp][x];
            float3 r0 = *(const float3*)&RSm[sAm][x];
            float3 r1 = *(const float3*)&RSm[sAc][x];
            float3 r2 = *(const float3*)&RSm[sAp][x];
#pragma unroll
            for (int j = 0; j < 3; ++j) {
                rAf[0][j] = rAf[1][j]; rAf[1][j] = rAf[2][j];
                rAm[0][j] = rAm[1][j]; rAm[1][j] = rAm[2][j];
            }
            rAf[2][0] = q0.x + q1.x + q2.x;
            rAf[2][1] = q0.y + q1.y + q2.y;
            rAf[2][2] = q0.z + q1.z + q2.z;
            rAm[2][0] = r0.x + r1.x + r2.x;
            rAm[2][1] = r0.y + r1.y + r2.y;
            rAm[2][2] = r0.z + r1.z + r2.z;
        }
        if (hasB) {
            float3 q0 = *(const float3*)&RSf[sBm][x];
            float3 q1 = *(const float3*)&RSf[sBc][x];
            float3 q2 = *(const float3*)&RSf[sBp][x];
            float3 r0 = *(const float3*)&RSm[sBm][x];
            float3 r1 = *(const float3*)&RSm[sBc][x];
            float3 r2 = *(const float3*)&RSm[sBp][x];
#pragma unroll
            for (int j = 0; j < 3; ++j) {
                rBf[0][j] = rBf[1][j]; rBf[1][j] = rBf[2][j];
                rBm[0][j] = rBm[1][j]; rBm[1][j] = rBm[2][j];
            }
            rBf[2][0] = q0.x + q1.x + q2.x;
            rBf[2][1] = q0.y + q1.y + q2.y;
            rBf[2][2] = q0.z + q1.z + q2.z;
            rBm[2][0] = r0.x + r1.x + r2.x;
            rBm[2][1] = r0.y + r1.y + r2.y;
            rBm[2][2] = r0.z + r1.z + r2.z;
        }

        // ---------------- products at zp = zc-1 ----------------
        const int  zp   = zc - 1;
        const bool stg  = (zp >= zpLo);
        const bool live = stg && (zp <= zpHi);

        if (live) {
            const size_t poff = (size_t)zp * DD;
            {
                const float* fv = f + poff + (size_t)prowA * DIM + x;
                const float* mv = m + poff + (size_t)prowA * DIM + x;
                float cf0 = fv[0], cf1 = fv[1], cf2 = fv[2];
                float cm0 = mv[0], cm1 = mv[1], cm2 = mv[2];
                float uf0 = (rAf[0][0] + rAf[1][0] + rAf[2][0]) * INV27;
                float uf1 = (rAf[0][1] + rAf[1][1] + rAf[2][1]) * INV27;
                float uf2 = (rAf[0][2] + rAf[1][2] + rAf[2][2]) * INV27;
                float um0 = (rAm[0][0] + rAm[1][0] + rAm[2][0]) * INV27;
                float um1 = (rAm[0][1] + rAm[1][1] + rAm[2][1]) * INV27;
                float um2 = (rAm[0][2] + rAm[1][2] + rAm[2][2]) * INV27;
                float dF0 = cf0 - uf0, dF1 = cf1 - uf1, dF2 = cf2 - uf2;
                float dM0 = cm0 - um0, dM1 = cm1 - um1, dM2 = cm2 - um2;
                float qc0 = dF0 * dM0, qc1 = dF1 * dM1, qc2 = dF2 * dM2;
                float qf0 = dF0 * dF0, qf1 = dF1 * dF1, qf2 = dF2 * dF2;
                float qm0 = dM0 * dM0, qm1 = dM1 * dM1, qm2 = dM2 * dM2;
                float cL = __shfl(qc2, t - 1); cL = (t == 0)  ? qc0 : cL;
                float cR = __shfl(qc0, t + 1); cR = (t == 63) ? qc2 : cR;
                float fL = __shfl(qf2, t - 1); fL = (t == 0)  ? qf0 : fL;
                float fR = __shfl(qf0, t + 1); fR = (t == 63) ? qf2 : fR;
                float mL = __shfl(qm2, t - 1); mL = (t == 0)  ? qm0 : mL;
                float mR = __shfl(qm0, t + 1); mR = (t == 63) ? qm2 : mR;
                *(float3*)&PRS[0][tA][x] = make_float3(cL + qc0 + qc1, qc0 + qc1 + qc2, qc1 + qc2 + cR);
                *(float3*)&PRS[1][tA][x] = make_float3(fL + qf0 + qf1, qf0 + qf1 + qf2, qf1 + qf2 + fR);
                *(float3*)&PRS[2][tA][x] = make_float3(mL + qm0 + qm1, qm0 + qm1 + qm2, qm1 + qm2 + mR);
            }
            if (hasB) {
                const float* fv = f + poff + (size_t)prowB * DIM + x;
                const float* mv = m + poff + (size_t)prowB * DIM + x;
                float cf0 = fv[0], cf1 = fv[1], cf2 = fv[2];
                float cm0 = mv[0], cm1 = mv[1], cm2 = mv[2];
                float uf0 = (rBf[0][0] + rBf[1][0] + rBf[2][0]) * INV27;
                float uf1 = (rBf[0][1] + rBf[1][1] + rBf[2][1]) * INV27;
                float uf2 = (rBf[0][2] + rBf[1][2] + rBf[2][2]) * INV27;
                float um0 = (rBm[0][0] + rBm[1][0] + rBm[2][0]) * INV27;
                float um1 = (rBm[0][1] + rBm[1][1] + rBm[2][1]) * INV27;
                float um2 = (rBm[0][2] + rBm[1][2] + rBm[2][2]) * INV27;
                float dF0 = cf0 - uf0, dF1 = cf1 - uf1, dF2 = cf2 - uf2;
                float dM0 = cm0 - um0, dM1 = cm1 - um1, dM2 = cm2 - um2;
                float qc0 = dF0 * dM0, qc1 = dF1 * dM1, qc2 = dF2 * dM2;
                float qf0 = dF0 * dF0, qf1 = dF1 * dF1, qf2 = dF2 * dF2;
                float qm0 = dM0 * dM0, qm1 = dM1 * dM1, qm2 = dM2 * dM2;
                float cL = __shfl(qc2, t - 1); cL = (t == 0)  ? qc0 : cL;
                float cR = __shfl(qc0, t + 1); cR = (t == 63) ? qc2 : cR;
                float fL = __shfl(qf2, t - 1); fL = (t == 0)  ? qf0 : fL;
                float fR = __shfl(qf0, t + 1); fR = (t == 63) ? qf2 : fR;
                float mL = __shfl(qm2, t - 1); mL = (t == 0)  ? qm0 : mL;
                float mR = __shfl(qm0, t + 1); mR = (t == 63) ? qm2 : mR;
                *(float3*)&PRS[0][tB][x] = make_float3(cL + qc0 + qc1, qc0 + qc1 + qc2, qc1 + qc2 + cR);
                *(float3*)&PRS[1][tB][x] = make_float3(fL + qf0 + qf1, qf0 + qf1 + qf2, qf1 + qf2 + fR);
                *(float3*)&PRS[2][tB][x] = make_float3(mL + qm0 + qm1, qm0 + qm1 + qm2, qm1 + qm2 + mR);
            }
        }
        __syncthreads();

        // ---------------- output at z = zc-2 ----------------
        if (stg) {
#pragma unroll
            for (int i = 0; i < 9; ++i) { pmv[i] = pcv[i]; pcv[i] = pnv[i]; }
            if (live) {
#pragma unroll
                for (int q = 0; q < 3; ++q) {
                    float3 u0 = *(const float3*)&PRS[q][tOm][x];
                    float3 u1 = *(const float3*)&PRS[q][tOc][x];
                    float3 u2 = *(const float3*)&PRS[q][tOp][x];
                    pnv[q * 3 + 0] = u0.x + u1.x + u2.x;
                    pnv[q * 3 + 1] = u0.y + u1.y + u2.y;
                    pnv[q * 3 + 2] = u0.z + u1.z + u2.z;
                }
            }
            const int z = zc - 2;
            if (z >= z0 && z < z1) {
#pragma unroll
                for (int j = 0; j < 3; ++j) {
                    float a0 = (z == 0) ? pcv[j]     : pmv[j];
                    float a1 = (z == 0) ? pcv[3 + j] : pmv[3 + j];
                    float a2 = (z == 0) ? pcv[6 + j] : pmv[6 + j];
                    float c0 = (z == DIM - 1) ? pcv[j]     : pnv[j];
                    float c1 = (z == DIM - 1) ? pcv[3 + j] : pnv[3 + j];
                    float c2 = (z == DIM - 1) ? pcv[6 + j] : pnv[6 + j];
                    float cross = a0 + pcv[j]     + c0;
                    float vF    = a1 + pcv[3 + j] + c1;
                    float vM    = a2 + pcv[6 + j] + c2;
                    accz += cross * cross / (vF * vM + EPS);
                }
            }
        }
    }

    // ---- block reduction -> global accumulator ----
    float s = accz;
#pragma unroll
    for (int off = 32; off > 0; off >>= 1) s += __shfl_down(s, off, 64);
    if (t == 0) wred[w] = s;
    __syncthreads();
    if (tid == 0) {
        float tot = 0.f;
#pragma unroll
        for (int i = 0; i < 8; ++i) tot += wred[i];
        atomicAdd(&acc[b], (double)tot);
    }
}

__global__ void finalize_kernel(const double* __restrict__ acc,
                                float* __restrict__ out)
{
    int i = threadIdx.x;
    if (i < 2) out[i] = (float)(-acc[i] / (double)DDD);
}

extern "C" void kernel_launch(void* const* d_in, const int* in_sizes, int n_in,
                              void* d_out, int out_size, void* d_ws, size_t ws_size,
                              hipStream_t stream)
{
    const float* F = (const float*)d_in[0];   // im_fixed  [2,1,192,192,192] f32
    const float* M = (const float*)d_in[1];   // im_moving
    float* out = (float*)d_out;               // [2] f32

    double* acc = (double*)d_ws;
    hipMemsetAsync(d_ws, 0, 2 * sizeof(double), stream);

    dim3 grid(DIM / ZC, DIM / TY, 2);   // 16 x 24 x 2 = 768 blocks, 512 thr
    lcc_fused<<<grid, 512, 0, stream>>>(F, M, acc);
    finalize_kernel<<<1, 64, 0, stream>>>(acc, out);
}

// Round 5
// 195.829 us; speedup vs baseline: 5.1346x; 1.0805x over previous
//
#include <hip/hip_runtime.h>

#define DIM 192
#define DD  (DIM * DIM)
#define DDD (DIM * DIM * DIM)
#define INV27 (1.0f / 27.0f)
#define EPS 1e-5f

#define TY 8          // output rows per block (1 per wave)
#define ZC 12         // output planes per block -> 16 z-chunks, grid 768
#define NRS (TY + 4)  // 12 rowsum slots
#define NPR (TY + 2)  // 10 product slots

__device__ __forceinline__ int iclamp(int v, int hi) {
    return v < 0 ? 0 : (v > hi ? hi : v);
}

// ---------------------------------------------------------------------------
// Wave-per-row fused LCC, software-pipelined:
// per iteration zc:
//   P0: issue global loads (stage-1 rows, plane zc), SCALAR components
//   P1: output stage for zo = zc-3 (PRS reads + PS ring)  [reg/LDS only]
//   P2: stage-1 x-rowsums (consume P0 regs) -> RS in LDS
//   BAR1
//   P3: product-center loads (plane zc-1, L1-hot) issued first; S2D ring push
//       from RS; dF,dM -> products -> x-rowsums -> PRS in LDS
//   BAR2
// NOTE: never cast GLOBAL pointers to float3 (clang widens vec3 loads to 16B
// -> OOB fault at buffer end). LDS float3 (b96) is proven safe (round 3).
// ---------------------------------------------------------------------------
__global__ __launch_bounds__(512) void lcc_fused(
    const float* __restrict__ F, const float* __restrict__ M,
    float* __restrict__ out)
{
    __shared__ float RSf[NRS][DIM];
    __shared__ float RSm[NRS][DIM];
    __shared__ float PRS[3][NPR][DIM];   // 0=cross 1=ff 2=mm
    __shared__ float wred[8];

    const int tid = threadIdx.x;
    const int w   = tid >> 6;     // wave 0..7
    const int t   = tid & 63;     // lane
    const int x   = 3 * t;

    const int y0 = blockIdx.y * TY;
    const int z0 = blockIdx.x * ZC;
    const int z1 = z0 + ZC;
    const int b  = blockIdx.z;

    const float* f = F + (size_t)b * DDD;
    const float* m = M + (size_t)b * DDD;

    // stage-1 rowsum tasks: slot s holds row clamp(y0-2+s)
    const int  row1a = iclamp(y0 - 2 + w, DIM - 1);         // slot w
    const bool has1b = (w < NRS - 8);                       // waves 0..3
    const int  row1b = iclamp(y0 + 6 + w, DIM - 1);         // slot 8+w

    // product tasks: slot tt holds product row clamp(y0-1+tt)
    const int  tA    = w + 1;
    const int  prowA = iclamp(y0 - 1 + tA, DIM - 1);
    const bool hasB  = (w == 0) || (w == 7);
    const int  tB    = (w == 0) ? 0 : NPR - 1;
    const int  prowB = iclamp(y0 - 1 + tB, DIM - 1);

    // S2D y-window RS slots (double-clamped)
    const int sAm = iclamp(prowA - 1, DIM - 1) - y0 + 2;
    const int sAc = prowA - y0 + 2;
    const int sAp = iclamp(prowA + 1, DIM - 1) - y0 + 2;
    const int sBm = iclamp(prowB - 1, DIM - 1) - y0 + 2;
    const int sBc = prowB - y0 + 2;
    const int sBp = iclamp(prowB + 1, DIM - 1) - y0 + 2;

    // output row & its PRS window slots
    const int yo  = y0 + w;
    const int tOm = iclamp(yo - 1, DIM - 1) - y0 + 1;
    const int tOc = w + 1;
    const int tOp = iclamp(yo + 1, DIM - 1) - y0 + 1;

    const int zpLo = (z0 - 1 > 0) ? z0 - 1 : 0;
    const int zpHi = (z1 < DIM - 1) ? z1 : DIM - 1;
    const int zcStart = (z0 - 2 > -1) ? z0 - 2 : -1;
    const int zcEnd   = z1 + 2;

    // per-wave register rings
    float rAf[3][3], rAm[3][3], rBf[3][3], rBm[3][3];
    float pmv[9], pcv[9], pnv[9];
#pragma unroll
    for (int i = 0; i < 3; ++i)
#pragma unroll
        for (int j = 0; j < 3; ++j) {
            rAf[i][j] = 0.f; rAm[i][j] = 0.f; rBf[i][j] = 0.f; rBm[i][j] = 0.f;
        }
#pragma unroll
    for (int i = 0; i < 9; ++i) { pmv[i] = 0.f; pcv[i] = 0.f; pnv[i] = 0.f; }

    float accz = 0.f;

    for (int zc = zcStart; zc <= zcEnd; ++zc) {
        const bool doLoad = (zc <= zpHi + 1);
        const int zcl = iclamp(zc, DIM - 1);
        const size_t zoff = (size_t)zcl * DD;

        // ---------------- P0: issue stage-1 global loads (scalar) ----------------
        float fa0 = 0, fa1 = 0, fa2 = 0, ma0 = 0, ma1 = 0, ma2 = 0;
        float fb0 = 0, fb1 = 0, fb2 = 0, mb0 = 0, mb1 = 0, mb2 = 0;
        if (doLoad) {
            const float* fr = f + zoff + (size_t)row1a * DIM + x;
            const float* mr = m + zoff + (size_t)row1a * DIM + x;
            fa0 = fr[0]; fa1 = fr[1]; fa2 = fr[2];
            ma0 = mr[0]; ma1 = mr[1]; ma2 = mr[2];
            if (has1b) {
                const float* fr2 = f + zoff + (size_t)row1b * DIM + x;
                const float* mr2 = m + zoff + (size_t)row1b * DIM + x;
                fb0 = fr2[0]; fb1 = fr2[1]; fb2 = fr2[2];
                mb0 = mr2[0]; mb1 = mr2[1]; mb2 = mr2[2];
            }
        }

        // ---------------- P1: output stage for zo = zc-3 ----------------
        {
            const int zq = zc - 2;            // plane currently held in PRS
            if (zq >= zpLo) {
#pragma unroll
                for (int i = 0; i < 9; ++i) { pmv[i] = pcv[i]; pcv[i] = pnv[i]; }
                if (zq <= zpHi) {
#pragma unroll
                    for (int q = 0; q < 3; ++q) {
                        float3 u0 = *(const float3*)&PRS[q][tOm][x];
                        float3 u1 = *(const float3*)&PRS[q][tOc][x];
                        float3 u2 = *(const float3*)&PRS[q][tOp][x];
                        pnv[q * 3 + 0] = u0.x + u1.x + u2.x;
                        pnv[q * 3 + 1] = u0.y + u1.y + u2.y;
                        pnv[q * 3 + 2] = u0.z + u1.z + u2.z;
                    }
                }
                const int zo = zc - 3;
                if (zo >= z0 && zo < z1) {
#pragma unroll
                    for (int j = 0; j < 3; ++j) {
                        float a0 = (zo == 0) ? pcv[j]     : pmv[j];
                        float a1 = (zo == 0) ? pcv[3 + j] : pmv[3 + j];
                        float a2 = (zo == 0) ? pcv[6 + j] : pmv[6 + j];
                        float c0 = (zo == DIM - 1) ? pcv[j]     : pnv[j];
                        float c1 = (zo == DIM - 1) ? pcv[3 + j] : pnv[3 + j];
                        float c2 = (zo == DIM - 1) ? pcv[6 + j] : pnv[6 + j];
                        float cross = a0 + pcv[j]     + c0;
                        float vF    = a1 + pcv[3 + j] + c1;
                        float vM    = a2 + pcv[6 + j] + c2;
                        accz += cross * cross / (vF * vM + EPS);
                    }
                }
            }
        }

        // ---------------- P2: stage-1 x-rowsums -> RS ----------------
        if (doLoad) {
            {
                float aL = __shfl(fa2, t - 1); aL = (t == 0)  ? fa0 : aL;
                float aR = __shfl(fa0, t + 1); aR = (t == 63) ? fa2 : aR;
                float cL = __shfl(ma2, t - 1); cL = (t == 0)  ? ma0 : cL;
                float cR = __shfl(ma0, t + 1); cR = (t == 63) ? ma2 : cR;
                *(float3*)&RSf[w][x] = make_float3(aL + fa0 + fa1, fa0 + fa1 + fa2, fa1 + fa2 + aR);
                *(float3*)&RSm[w][x] = make_float3(cL + ma0 + ma1, ma0 + ma1 + ma2, ma1 + ma2 + cR);
            }
            if (has1b) {
                float aL = __shfl(fb2, t - 1); aL = (t == 0)  ? fb0 : aL;
                float aR = __shfl(fb0, t + 1); aR = (t == 63) ? fb2 : aR;
                float cL = __shfl(mb2, t - 1); cL = (t == 0)  ? mb0 : cL;
                float cR = __shfl(mb0, t + 1); cR = (t == 63) ? mb2 : cR;
                *(float3*)&RSf[8 + w][x] = make_float3(aL + fb0 + fb1, fb0 + fb1 + fb2, fb1 + fb2 + aR);
                *(float3*)&RSm[8 + w][x] = make_float3(cL + mb0 + mb1, mb0 + mb1 + mb2, mb1 + mb2 + cR);
            }
        }
        __syncthreads();   // BAR1

        // ---------------- P3: center loads + S2D push + products ----------------
        const int  zp    = zc - 1;
        const bool liveP = (zp >= zpLo) && (zp <= zpHi);

        // issue product-center loads first (L1-hot; latency hides under S2D reads)
        float cfA0 = 0, cfA1 = 0, cfA2 = 0, cmA0 = 0, cmA1 = 0, cmA2 = 0;
        float cfB0 = 0, cfB1 = 0, cfB2 = 0, cmB0 = 0, cmB1 = 0, cmB2 = 0;
        if (liveP) {
            const size_t poff = (size_t)zp * DD;
            const float* fv = f + poff + (size_t)prowA * DIM + x;
            const float* mv = m + poff + (size_t)prowA * DIM + x;
            cfA0 = fv[0]; cfA1 = fv[1]; cfA2 = fv[2];
            cmA0 = mv[0]; cmA1 = mv[1]; cmA2 = mv[2];
            if (hasB) {
                const float* fv2 = f + poff + (size_t)prowB * DIM + x;
                const float* mv2 = m + poff + (size_t)prowB * DIM + x;
                cfB0 = fv2[0]; cfB1 = fv2[1]; cfB2 = fv2[2];
                cmB0 = mv2[0]; cmB1 = mv2[1]; cmB2 = mv2[2];
            }
        }

        if (doLoad) {
            {
                float3 q0 = *(const float3*)&RSf[sAm][x];
                float3 q1 = *(const float3*)&RSf[sAc][x];
                float3 q2 = *(const float3*)&RSf[sAp][x];
                float3 r0 = *(const float3*)&RSm[sAm][x];
                float3 r1 = *(const float3*)&RSm[sAc][x];
                float3 r2 = *(const float3*)&RSm[sAp][x];
#pragma unroll
                for (int j = 0; j < 3; ++j) {
                    rAf[0][j] = rAf[1][j]; rAf[1][j] = rAf[2][j];
                    rAm[0][j] = rAm[1][j]; rAm[1][j] = rAm[2][j];
                }
                rAf[2][0] = q0.x + q1.x + q2.x;
                rAf[2][1] = q0.y + q1.y + q2.y;
                rAf[2][2] = q0.z + q1.z + q2.z;
                rAm[2][0] = r0.x + r1.x + r2.x;
                rAm[2][1] = r0.y + r1.y + r2.y;
                rAm[2][2] = r0.z + r1.z + r2.z;
            }
            if (hasB) {
                float3 q0 = *(const float3*)&RSf[sBm][x];
                float3 q1 = *(const float3*)&RSf[sBc][x];
                float3 q2 = *(const float3*)&RSf[sBp][x];
                float3 r0 = *(const float3*)&RSm[sBm][x];
                float3 r1 = *(const float3*)&RSm[sBc][x];
                float3 r2 = *(const float3*)&RSm[sBp][x];
#pragma unroll
                for (int j = 0; j < 3; ++j) {
                    rBf[0][j] = rBf[1][j]; rBf[1][j] = rBf[2][j];
                    rBm[0][j] = rBm[1][j]; rBm[1][j] = rBm[2][j];
                }
                rBf[2][0] = q0.x + q1.x + q2.x;
                rBf[2][1] = q0.y + q1.y + q2.y;
                rBf[2][2] = q0.z + q1.z + q2.z;
                rBm[2][0] = r0.x + r1.x + r2.x;
                rBm[2][1] = r0.y + r1.y + r2.y;
                rBm[2][2] = r0.z + r1.z + r2.z;
            }
        }

        if (liveP) {
            {
                float uf0 = (rAf[0][0] + rAf[1][0] + rAf[2][0]) * INV27;
                float uf1 = (rAf[0][1] + rAf[1][1] + rAf[2][1]) * INV27;
                float uf2 = (rAf[0][2] + rAf[1][2] + rAf[2][2]) * INV27;
                float um0 = (rAm[0][0] + rAm[1][0] + rAm[2][0]) * INV27;
                float um1 = (rAm[0][1] + rAm[1][1] + rAm[2][1]) * INV27;
                float um2 = (rAm[0][2] + rAm[1][2] + rAm[2][2]) * INV27;
                float dF0 = cfA0 - uf0, dF1 = cfA1 - uf1, dF2 = cfA2 - uf2;
                float dM0 = cmA0 - um0, dM1 = cmA1 - um1, dM2 = cmA2 - um2;
                float qc0 = dF0 * dM0, qc1 = dF1 * dM1, qc2 = dF2 * dM2;
                float qf0 = dF0 * dF0, qf1 = dF1 * dF1, qf2 = dF2 * dF2;
                float qm0 = dM0 * dM0, qm1 = dM1 * dM1, qm2 = dM2 * dM2;
                float cL = __shfl(qc2, t - 1); cL = (t == 0)  ? qc0 : cL;
                float cR = __shfl(qc0, t + 1); cR = (t == 63) ? qc2 : cR;
                float fL = __shfl(qf2, t - 1); fL = (t == 0)  ? qf0 : fL;
                float fR = __shfl(qf0, t + 1); fR = (t == 63) ? qf2 : fR;
                float mL = __shfl(qm2, t - 1); mL = (t == 0)  ? qm0 : mL;
                float mR = __shfl(qm0, t + 1); mR = (t == 63) ? qm2 : mR;
                *(float3*)&PRS[0][tA][x] = make_float3(cL + qc0 + qc1, qc0 + qc1 + qc2, qc1 + qc2 + cR);
                *(float3*)&PRS[1][tA][x] = make_float3(fL + qf0 + qf1, qf0 + qf1 + qf2, qf1 + qf2 + fR);
                *(float3*)&PRS[2][tA][x] = make_float3(mL + qm0 + qm1, qm0 + qm1 + qm2, qm1 + qm2 + mR);
            }
            if (hasB) {
                float uf0 = (rBf[0][0] + rBf[1][0] + rBf[2][0]) * INV27;
                float uf1 = (rBf[0][1] + rBf[1][1] + rBf[2][1]) * INV27;
                float uf2 = (rBf[0][2] + rBf[1][2] + rBf[2][2]) * INV27;
                float um0 = (rBm[0][0] + rBm[1][0] + rBm[2][0]) * INV27;
                float um1 = (rBm[0][1] + rBm[1][1] + rBm[2][1]) * INV27;
                float um2 = (rBm[0][2] + rBm[1][2] + rBm[2][2]) * INV27;
                float dF0 = cfB0 - uf0, dF1 = cfB1 - uf1, dF2 = cfB2 - uf2;
                float dM0 = cmB0 - um0, dM1 = cmB1 - um1, dM2 = cmB2 - um2;
                float qc0 = dF0 * dM0, qc1 = dF1 * dM1, qc2 = dF2 * dM2;
                float qf0 = dF0 * dF0, qf1 = dF1 * dF1, qf2 = dF2 * dF2;
                float qm0 = dM0 * dM0, qm1 = dM1 * dM1, qm2 = dM2 * dM2;
                float cL = __shfl(qc2, t - 1); cL = (t == 0)  ? qc0 : cL;
                float cR = __shfl(qc0, t + 1); cR = (t == 63) ? qc2 : cR;
                float fL = __shfl(qf2, t - 1); fL = (t == 0)  ? qf0 : fL;
                float fR = __shfl(qf0, t + 1); fR = (t == 63) ? qf2 : fR;
                float mL = __shfl(qm2, t - 1); mL = (t == 0)  ? qm0 : mL;
                float mR = __shfl(qm0, t + 1); mR = (t == 63) ? qm2 : mR;
                *(float3*)&PRS[0][tB][x] = make_float3(cL + qc0 + qc1, qc0 + qc1 + qc2, qc1 + qc2 + cR);
                *(float3*)&PRS[1][tB][x] = make_float3(fL + qf0 + qf1, qf0 + qf1 + qf2, qf1 + qf2 + fR);
                *(float3*)&PRS[2][tB][x] = make_float3(mL + qm0 + qm1, qm0 + qm1 + qm2, qm1 + qm2 + mR);
            }
        }
        __syncthreads();   // BAR2
    }

    // ---- block reduction -> output (finalize fused, f32 atomic) ----
    float s = accz;
#pragma unroll
    for (int off = 32; off > 0; off >>= 1) s += __shfl_down(s, off, 64);
    if (t == 0) wred[w] = s;
    __syncthreads();
    if (tid == 0) {
        float tot = 0.f;
#pragma unroll
        for (int i = 0; i < 8; ++i) tot += wred[i];
        atomicAdd(&out[b], tot * (-1.0f / (float)DDD));
    }
}

extern "C" void kernel_launch(void* const* d_in, const int* in_sizes, int n_in,
                              void* d_out, int out_size, void* d_ws, size_t ws_size,
                              hipStream_t stream)
{
    const float* F = (const float*)d_in[0];   // im_fixed  [2,1,192,192,192] f32
    const float* M = (const float*)d_in[1];   // im_moving
    float* out = (float*)d_out;               // [2] f32

    hipMemsetAsync(d_out, 0, (size_t)out_size * sizeof(float), stream);

    dim3 grid(DIM / ZC, DIM / TY, 2);   // 16 x 24 x 2 = 768 blocks, 512 thr
    lcc_fused<<<grid, 512, 0, stream>>>(F, M, out);
}